// Round 9
// baseline (971.357 us; speedup 1.0000x reference)
//
#include <hip/hip_runtime.h>
#include <cmath>

#define B_   32
#define S_   128
#define E_   300
#define C_   100
#define EC_  50
#define LC_  50
#define H_   256
#define G4_  1024   // 4*H
#define L_   17
#define DHID_ 400   // E + C
#define SLAB_ 8192  // u32 per (d,t) frag slab: [Nt(2)][Kt(8)][lane(64)][hi m0..3 | lo m4..7]
#define SENT2_ 0x7E007E00u  // fp16-NaN in both halves: legit packed pair never matches
#define KP_   208   // k-pairs per row in packed GEMM operands (416 k, zero-padded from 400)

// ---- mega layout: 32 LSTM blocks (1/CU via 84KB LDS) + up to 224 queue workers ----
#define NB_LSTM   32
#define NBLK_MEGA 256
#define NTILE_G   512
#define NIT_PW    64    // prep_w chunks of 6656 u32 (64*6656 = 2*G4_*KP_)
#define NIT_PB    128   // prep_b row-groups of 32
#define NIT_C1    64
#define NIT_C2    128
#define NIT_C3    160

// ---- k_tail role layout ----
#define TRB_FC   0
#define TNB_FC   128
#define TRB_SMV  128
#define TNB_SMV  32
#define NBLK_TAIL 160

// flags: each id padded 32 ints (128 B) apart -> no false sharing
#define F_HF   0
#define D_PW   1
#define D_PBE  2
#define D_C1   3
#define D_C2   4
#define D_C3   5
#define D_PB   6
#define F_EM   7
#define FG(d, rt) (8 + (d) * 32 + (rt))   // 8..71, target 8 each
#define Q_PW   72
#define Q_PB1  73
#define Q_C1   74
#define Q_C2   75
#define Q_C3   76
#define Q_PB2  77
#define Q_G    78
#define FLG(i)    ((i) * 32)
#define NFLAGS_   (80 * 32)

typedef _Float16 half8 __attribute__((ext_vector_type(8)));
typedef float f32x4 __attribute__((ext_vector_type(4)));
typedef unsigned long long ull;
struct __align__(16) U2 { ull x, y; };

// split fp32 -> (hi fp16, lo fp16 scaled by 2048), packed u32 (hi in low16).
__device__ __forceinline__ unsigned pack_split(float v) {
  _Float16 hi = (fabsf(v) >= 6.104e-5f) ? (_Float16)v : (_Float16)0.0f;
  float hif = (float)hi;
  _Float16 lo = (_Float16)((v - hif) * 2048.0f);
  return (unsigned)__builtin_bit_cast(unsigned short, hi)
       | ((unsigned)__builtin_bit_cast(unsigned short, lo) << 16);
}

__device__ __forceinline__ void flag_signal(int* f) {
  __syncthreads();   // all threads' stores drained; release add -> L2 writeback
  if (threadIdx.x == 0)
    __hip_atomic_fetch_add(f, 1, __ATOMIC_RELEASE, __HIP_MEMORY_SCOPE_AGENT);
}
__device__ __forceinline__ void flag_wait(const int* f, int target) {
  while (__hip_atomic_load(f, __ATOMIC_ACQUIRE, __HIP_MEMORY_SCOPE_AGENT) < target)
    __builtin_amdgcn_s_sleep(8);
}

// 84 KB pad forces 1 block/CU (2x84 > 160 KB): LSTM blocks get exclusive CUs — the
// R5-measured +107us co-residency tax is structurally impossible.
union SMemMega {
  char pad[84 * 1024];
  struct { unsigned aH[2048], aL[2048], bH[2048], bL[2048]; } gemm;                       // 32 KB
  struct { ull slh[2048], sll[2048]; float gl[4 * 16 * 33]; unsigned ps[2 * 576]; } lstm; // 45.3 KB
  struct { float ce[EC_ * 52]; float wl[50 * 150]; int ids[LC_]; } c1;
  struct { float il[C_ * 48]; float wl[25 * 400]; } c2;                                    // 59.2 KB
  struct { float il[C_ * 45]; float wl[20 * 500]; float o3[20 * 44]; } c3;                 // 61.5 KB
};

// ---------------------------------------------------------------- mega: LSTM (exclusive CUs) + queue workers
__global__ __launch_bounds__(256) void k_mega(
    const int* __restrict__ x, const int* __restrict__ x_char,
    const float* __restrict__ word_emb, const float* __restrict__ char_emb,
    const float* __restrict__ conv1_w, const float* __restrict__ conv1_b,
    const float* __restrict__ conv2_w, const float* __restrict__ conv2_b,
    const float* __restrict__ conv3_w, const float* __restrict__ conv3_b,
    const float* __restrict__ w_ih_f, const float* __restrict__ w_ih_b,
    const float* __restrict__ w_hh_f, const float* __restrict__ w_hh_b,
    const float* __restrict__ b_f, const float* __restrict__ b_b,
    const float* __restrict__ h0, const float* __restrict__ c0,
    float* __restrict__ pooled, float* __restrict__ gi, float* __restrict__ hbuf,
    unsigned* __restrict__ hfrag,
    unsigned* __restrict__ apH, unsigned* __restrict__ apL,
    unsigned* __restrict__ bpH, unsigned* __restrict__ bpL,
    float* __restrict__ out1, float* __restrict__ out2,
    int* __restrict__ flags) {
  const int bid = blockIdx.x;
  const int tid = threadIdx.x;
  __shared__ SMemMega sm;
  __shared__ int curq;

  // ================================================================ LSTM (bids 0..31)
  if (bid < NB_LSTM) {
    const int d = bid >> 4;
    const int iblk = bid & 15;
    const int Ktown = iblk >> 1;
    const int half = iblk & 1;
    const float* whh = d ? w_hh_b : w_hh_f;

    // ---- hfrag init: OWN REGION ONLY (Kt=Ktown, lanes [half*32, half*32+32), both Nt,
    // all t of direction d). Fill->produce is sequential within this block, so the
    // sentinel protocol cannot race even if F_HF is stale-satisfied (replay safety).
    {
      const int items = (S_ + 1) * 512;   // 2 Nt * 32 lanes * 8 m8 per slab
      for (int idx2 = tid; idx2 < items; idx2 += 256) {
        int t = idx2 >> 9;
        int within = idx2 & 511;
        int Nt = within >> 8;
        int rem = within & 255;
        int lane = half * 32 + (rem >> 3);
        int m8 = rem & 7;
        size_t u = (size_t)(d * (S_ + 1) + t) * SLAB_ +
                   (((size_t)(Nt * 8 + Ktown) * 64 + lane) * 8 + m8);
        if (t != 0) { hfrag[u] = SENT2_; continue; }
        int m = m8 & 3, isLo = m8 >> 2;
        int k0 = Ktown * 32 + (lane >> 4) * 8 + 2 * m;
        int b = Nt * 16 + (lane & 15);
        unsigned p0 = pack_split(h0[((size_t)d * B_ + b) * H_ + k0]);
        unsigned p1 = pack_split(h0[((size_t)d * B_ + b) * H_ + k0 + 1]);
        unsigned hiw = (p0 & 0xFFFFu) | (p1 << 16);
        unsigned low = (p0 >> 16) | (p1 & 0xFFFF0000u);
        hfrag[u] = isLo ? low : hiw;
      }
      flag_signal(&flags[FLG(F_HF)]);
      flag_wait(&flags[FLG(F_HF)], NB_LSTM);   // all 32 fills LLC-visible before any step
      __syncthreads();
    }

    const int w = tid >> 6;             // wave index = gate (i,f,g,o)
    const int l = tid & 63;
    const int lx = l & 15, lq = l >> 4;
    const int u0 = iblk * 16;

    ull* slh = sm.lstm.slh;
    ull* sll = sm.lstm.sll;
    float* glb = sm.lstm.gl;
    unsigned* ps = sm.lstm.ps;

    half8 whi[8], wlo[8];
#pragma unroll
    for (int Kt = 0; Kt < 8; ++Kt) {
      int row = w * H_ + u0 + lx;
      int kk0 = Kt * 32 + lq * 8;
      const float* src = whh + (size_t)row * H_ + kk0;
      float4 f0 = *(const float4*)src;
      float4 f1 = *(const float4*)(src + 4);
      float wv[8] = {f0.x, f0.y, f0.z, f0.w, f1.x, f1.y, f1.z, f1.w};
      union { unsigned short s2[8]; half8 h; } HI, LO;
#pragma unroll
      for (int j = 0; j < 8; ++j) {
        float v = wv[j];
        _Float16 hi = (fabsf(v) >= 6.104e-5f) ? (_Float16)v : (_Float16)0.0f;
        float hif = (float)hi;
        _Float16 lo = (_Float16)((v - hif) * 2048.0f);
        HI.s2[j] = __builtin_bit_cast(unsigned short, hi);
        LO.s2[j] = __builtin_bit_cast(unsigned short, lo);
      }
      whi[Kt] = HI.h;
      wlo[Kt] = LO.h;
    }

    const int bc = tid & 31, cw = tid >> 5;
    float creg[2];
#pragma unroll
    for (int cu = 0; cu < 2; ++cu)
      creg[cu] = c0[((size_t)d * B_ + bc) * H_ + u0 + cu * 8 + cw];

    const int pNt = bc >> 4;
    const int pm = cw >> 1;
    const bool phi = (cw & 1) == 0;
    const int plane = bc & 15;
    const float inv2048 = 1.0f / 2048.0f;

    int rt_have = -1;
    for (int t = 0; t < S_; ++t) {
      int torig = d ? (S_ - 1 - t) : t;

      // gate on GEMM tile completion for this 4-step r-range (R3-proven protocol)
      int rt = torig >> 2;
      if (rt != rt_have) {
        if (tid == 0) {
          const int* gf = &flags[FLG(FG(d, rt))];
          while (__hip_atomic_load(gf, __ATOMIC_ACQUIRE, __HIP_MEMORY_SCOPE_AGENT) < 8)
            __builtin_amdgcn_s_sleep(2);
        }
        __syncthreads();
        rt_have = rt;
      }

      // plain gi loads — in flight during the hfrag spin below
      f32x4 acch[2], accl[2];
      {
        const float* gbase = gi + ((size_t)(d * S_ + torig) * G4_) * B_;
#pragma unroll
        for (int Nt = 0; Nt < 2; ++Nt) {
          f32x4 v;
#pragma unroll
          for (int r = 0; r < 4; ++r) {
            int j = w * H_ + u0 + lq * 4 + r;
            v[r] = gbase[(size_t)j * B_ + Nt * 16 + lx];
          }
          acch[Nt] = v;
          f32x4 z = {0.f, 0.f, 0.f, 0.f};
          accl[Nt] = z;
        }
      }

      // spin on previous-step h fragments (unchanged protocol; full slab read)
      const ull* hp = (const ull*)(hfrag + (size_t)(d * (S_ + 1) + t) * SLAB_);
      ull pv[4][4];
#pragma unroll
      for (int c = 0; c < 4; ++c) {
        size_t base = ((size_t)(w * 4 + c) * 64 + l) * 4;
#pragma unroll
        for (int j = 0; j < 4; ++j)
          pv[c][j] = __hip_atomic_load(&hp[base + j], __ATOMIC_RELAXED,
                                       __HIP_MEMORY_SCOPE_AGENT);
      }
      for (;;) {
        bool pending = false;
#pragma unroll
        for (int c = 0; c < 4; ++c)
#pragma unroll
          for (int j = 0; j < 4; ++j)
            pending |= ((unsigned)pv[c][j] == SENT2_) |
                       ((unsigned)(pv[c][j] >> 32) == SENT2_);
        if (!pending) break;
#pragma unroll
        for (int c = 0; c < 4; ++c) {
          size_t base = ((size_t)(w * 4 + c) * 64 + l) * 4;
#pragma unroll
          for (int j = 0; j < 4; ++j)
            pv[c][j] = __hip_atomic_load(&hp[base + j], __ATOMIC_RELAXED,
                                         __HIP_MEMORY_SCOPE_AGENT);
        }
      }
#pragma unroll
      for (int c = 0; c < 4; ++c) {
        int idx = ((w * 4 + c) * 64 + l) * 2;
        U2 vh; vh.x = pv[c][0]; vh.y = pv[c][1];
        U2 vl; vl.x = pv[c][2]; vl.y = pv[c][3];
        *(U2*)&slh[idx] = vh;
        *(U2*)&sll[idx] = vl;
      }
      __syncthreads();

#pragma unroll
      for (int Kt = 0; Kt < 8; ++Kt) {
        half8 Bhi[2], Blo[2];
#pragma unroll
        for (int Nt = 0; Nt < 2; ++Nt) {
          int idx = ((Nt * 8 + Kt) * 64 + l) * 2;
          union { U2 u; half8 h; } UH, UL;
          UH.u = *(const U2*)&slh[idx];
          UL.u = *(const U2*)&sll[idx];
          Bhi[Nt] = UH.h;
          Blo[Nt] = UL.h;
        }
#pragma unroll
        for (int Nt = 0; Nt < 2; ++Nt) {
          acch[Nt] = __builtin_amdgcn_mfma_f32_16x16x32_f16(whi[Kt], Bhi[Nt], acch[Nt], 0, 0, 0);
          accl[Nt] = __builtin_amdgcn_mfma_f32_16x16x32_f16(whi[Kt], Blo[Nt], accl[Nt], 0, 0, 0);
          accl[Nt] = __builtin_amdgcn_mfma_f32_16x16x32_f16(wlo[Kt], Bhi[Nt], accl[Nt], 0, 0, 0);
        }
      }

#pragma unroll
      for (int Nt = 0; Nt < 2; ++Nt)
#pragma unroll
        for (int r = 0; r < 4; ++r) {
          int ul = lq * 4 + r;
          glb[(w * 16 + ul) * 33 + Nt * 16 + lx] = acch[Nt][r] + accl[Nt][r] * inv2048;
        }
      __syncthreads();

      float hreg[2];
#pragma unroll
      for (int cu = 0; cu < 2; ++cu) {
        int u = cu * 8 + cw;
        float g_i = glb[(0 * 16 + u) * 33 + bc];
        float g_f = glb[(1 * 16 + u) * 33 + bc];
        float g_g = glb[(2 * 16 + u) * 33 + bc];
        float g_o = glb[(3 * 16 + u) * 33 + bc];
        float si = 1.f / (1.f + __expf(-g_i));
        float sf = 1.f / (1.f + __expf(-g_f));
        float so = 1.f / (1.f + __expf(-g_o));
        float tg = 1.f - 2.f / (__expf(2.f * g_g) + 1.f);
        float cn = sf * creg[cu] + si * tg;
        float tc = 1.f - 2.f / (__expf(2.f * cn) + 1.f);
        float hn = so * tc;
        creg[cu] = cn;
        hreg[cu] = hn;
        unsigned me = pack_split(hn);
        unsigned pa = (unsigned)__shfl_xor((int)me, 32, 64);
        unsigned je = (cw & 1) ? pa : me;
        unsigned jo = (cw & 1) ? me : pa;
        unsigned hiw = (je & 0xFFFFu) | (jo << 16);
        unsigned low = (je >> 16) | (jo & 0xFFFF0000u);
        int lane2g = ((half * 2 + cu) << 4) | plane;
        int m8 = phi ? pm : (4 + pm);
        ps[pNt * 576 + lane2g * 9 + m8] = phi ? hiw : low;
      }
      __syncthreads();

      {
        ull* slab64 = (ull*)(hfrag + (size_t)(d * (S_ + 1) + t + 1) * SLAB_);
        int Nt = tid >> 7;
        int r = tid & 127;
        int lane2g = half * 32 + (r >> 2);
        int m2 = r & 3;
        unsigned a = ps[Nt * 576 + lane2g * 9 + 2 * m2];
        unsigned b2 = ps[Nt * 576 + lane2g * 9 + 2 * m2 + 1];
        ull v = (ull)a | ((ull)b2 << 32);
        __hip_atomic_store(&slab64[(size_t)(Nt * 8 + Ktown) * 256 + (size_t)half * 128 + r], v,
                           __ATOMIC_RELAXED, __HIP_MEMORY_SCOPE_AGENT);
        // hbuf: plain stores; consumer is k_tail (kernel-boundary coherence, R7-proven)
        float* hb = hbuf + (size_t)(d * (S_ + 1) + t + 1) * (H_ * B_) + u0 * B_;
        hb[0 * 256 + tid] = hreg[0];
        hb[1 * 256 + tid] = hreg[1];
      }
    }
    return;
  }

  // ================================================================ queue workers (bids 32..255)
  // NO all-worker barriers: every phase is an atomic work-queue + per-item done counter.
  // Any subset of resident workers drains all items; stragglers find empty queues.
  {
    // ---- prep_w: 64 chunks of 6656 u32
    for (;;) {
      __syncthreads();
      if (tid == 0)
        curq = __hip_atomic_fetch_add(&flags[FLG(Q_PW)], 1, __ATOMIC_RELAXED,
                                      __HIP_MEMORY_SCOPE_AGENT);
      __syncthreads();
      const int q = curq;
      if (q >= NIT_PW) break;
      const int base = q * 6656;
      for (int idx = base + tid; idx < base + 6656; idx += 256) {
        int d = idx / (G4_ * KP_);
        int rem = idx % (G4_ * KP_);
        int j = rem / KP_, k2 = rem % KP_;
        const float* w2 = d ? w_ih_b : w_ih_f;
        float v0 = 0.f, v1 = 0.f;
        if (k2 < 200) { v0 = w2[(size_t)j * DHID_ + 2 * k2]; v1 = w2[(size_t)j * DHID_ + 2 * k2 + 1]; }
        unsigned p0 = pack_split(v0), p1 = pack_split(v1);
        apH[idx] = (p0 & 0xFFFFu) | (p1 << 16);
        apL[idx] = (p0 >> 16) | (p1 & 0xFFFF0000u);
      }
      flag_signal(&flags[FLG(D_PW)]);
    }

    // ---- prep_b phase 1: emb part + zero pad (128 row-groups)
    for (;;) {
      __syncthreads();
      if (tid == 0)
        curq = __hip_atomic_fetch_add(&flags[FLG(Q_PB1)], 1, __ATOMIC_RELAXED,
                                      __HIP_MEMORY_SCOPE_AGENT);
      __syncthreads();
      const int q = curq;
      if (q >= NIT_PB) break;
      if (tid < KP_) {
        int k2 = tid;
        for (int rr = 0; rr < 32; ++rr) {
          int r = q * 32 + rr;
          int t2 = r >> 5, b2 = r & 31;
          if (k2 < 150) {
            const float* e2 = word_emb + (size_t)x[b2 * S_ + t2] * E_;
            unsigned p0 = pack_split(e2[2 * k2]), p1 = pack_split(e2[2 * k2 + 1]);
            bpH[(size_t)r * KP_ + k2] = (p0 & 0xFFFFu) | (p1 << 16);
            bpL[(size_t)r * KP_ + k2] = (p0 >> 16) | (p1 & 0xFFFF0000u);
          } else if (k2 >= 200) {
            bpH[(size_t)r * KP_ + k2] = 0u;
            bpL[(size_t)r * KP_ + k2] = 0u;
          }
        }
      }
      flag_signal(&flags[FLG(D_PBE)]);
    }

    // ---- conv1 (64 items)
    for (;;) {
      __syncthreads();
      if (tid == 0)
        curq = __hip_atomic_fetch_add(&flags[FLG(Q_C1)], 1, __ATOMIC_RELAXED,
                                      __HIP_MEMORY_SCOPE_AGENT);
      __syncthreads();
      const int q = curq;
      if (q >= NIT_C1) break;
      const int b2 = q & 31, ot = q >> 5;
      float* ce = sm.c1.ce;
      float* wl = sm.c1.wl;
      int* ids = sm.c1.ids;
      if (tid < LC_) ids[tid] = x_char[b2 * LC_ + tid];
      __syncthreads();
      for (int idx = tid; idx < LC_ * EC_; idx += 256) {
        int t2 = idx / EC_, ec = idx % EC_;
        ce[ec * 52 + t2] = char_emb[ids[t2] * EC_ + ec];
      }
      int obase = ot * 50;
      for (int idx = tid; idx < 50 * 150; idx += 256)
        wl[idx] = conv1_w[obase * 150 + idx];
      __syncthreads();
      for (int idx = tid; idx < 50 * 48; idx += 256) {
        int o = idx / 48, t2 = idx % 48;
        float acc = conv1_b[obase + o];
        const float* wr = &wl[o * 150];
        for (int c = 0; c < EC_; ++c) {
          const float* ip = &ce[c * 52 + t2];
          acc += wr[c * 3 + 0] * ip[0] + wr[c * 3 + 1] * ip[1] + wr[c * 3 + 2] * ip[2];
        }
        out1[((size_t)b2 * C_ + obase + o) * 48 + t2] = fmaxf(acc, 0.0f);
      }
      flag_signal(&flags[FLG(D_C1)]);
    }
    flag_wait(&flags[FLG(D_C1)], NIT_C1);

    // ---- conv2 (128 items)
    for (;;) {
      __syncthreads();
      if (tid == 0)
        curq = __hip_atomic_fetch_add(&flags[FLG(Q_C2)], 1, __ATOMIC_RELAXED,
                                      __HIP_MEMORY_SCOPE_AGENT);
      __syncthreads();
      const int q = curq;
      if (q >= NIT_C2) break;
      const int b2 = q & 31, ot = q >> 5;
      float* il = sm.c2.il;
      float* wl = sm.c2.wl;
      for (int idx = tid; idx < C_ * 48; idx += 256) il[idx] = out1[(size_t)b2 * C_ * 48 + idx];
      int obase = ot * 25;
      for (int idx = tid; idx < 25 * 400; idx += 256) wl[idx] = conv2_w[obase * 400 + idx];
      __syncthreads();
      for (int idx = tid; idx < 25 * 45; idx += 256) {
        int o = idx / 45, t2 = idx % 45;
        float acc = conv2_b[obase + o];
        const float* wr = &wl[o * 400];
        for (int c = 0; c < C_; ++c) {
          const float* ip = &il[c * 48 + t2];
          acc += wr[c * 4 + 0] * ip[0] + wr[c * 4 + 1] * ip[1] +
                 wr[c * 4 + 2] * ip[2] + wr[c * 4 + 3] * ip[3];
        }
        out2[((size_t)b2 * C_ + obase + o) * 45 + t2] = fmaxf(acc, 0.0f);
      }
      flag_signal(&flags[FLG(D_C2)]);
    }
    flag_wait(&flags[FLG(D_C2)], NIT_C2);

    // ---- conv3 + maxpool (160 items)
    for (;;) {
      __syncthreads();
      if (tid == 0)
        curq = __hip_atomic_fetch_add(&flags[FLG(Q_C3)], 1, __ATOMIC_RELAXED,
                                      __HIP_MEMORY_SCOPE_AGENT);
      __syncthreads();
      const int q = curq;
      if (q >= NIT_C3) break;
      const int b2 = q % 32, ot = q / 32;
      float* il = sm.c3.il;
      float* wl = sm.c3.wl;
      float* o3 = sm.c3.o3;
      for (int idx = tid; idx < C_ * 45; idx += 256) il[idx] = out2[(size_t)b2 * C_ * 45 + idx];
      int obase = ot * 20;
      for (int idx = tid; idx < 20 * 500; idx += 256) wl[idx] = conv3_w[obase * 500 + idx];
      __syncthreads();
      for (int idx = tid; idx < 20 * 41; idx += 256) {
        int o = idx / 41, t2 = idx % 41;
        float acc = conv3_b[obase + o];
        const float* wr = &wl[o * 500];
        for (int c = 0; c < C_; ++c) {
          const float* ip = &il[c * 45 + t2];
          acc += wr[c * 5 + 0] * ip[0] + wr[c * 5 + 1] * ip[1] + wr[c * 5 + 2] * ip[2] +
                 wr[c * 5 + 3] * ip[3] + wr[c * 5 + 4] * ip[4];
        }
        o3[o * 44 + t2] = fmaxf(acc, 0.0f);
      }
      __syncthreads();
      if (tid < 20) {
        float m = o3[tid * 44];
        for (int t2 = 1; t2 < 41; ++t2) m = fmaxf(m, o3[tid * 44 + t2]);
        pooled[b2 * C_ + obase + tid] = m;
      }
      flag_signal(&flags[FLG(D_C3)]);
    }
    flag_wait(&flags[FLG(D_C3)], NIT_C3);

    // ---- prep_b phase 2: pooled part (128 items; no LDS)
    for (;;) {
      __syncthreads();
      if (tid == 0)
        curq = __hip_atomic_fetch_add(&flags[FLG(Q_PB2)], 1, __ATOMIC_RELAXED,
                                      __HIP_MEMORY_SCOPE_AGENT);
      __syncthreads();
      const int q = curq;
      if (q >= NIT_PB) break;
      if (tid >= 150 && tid < 200) {
        int k2 = tid;
        for (int rr = 0; rr < 32; ++rr) {
          int r = q * 32 + rr;
          int b2 = r & 31;
          float v0 = pooled[b2 * C_ + 2 * k2 - 300];
          float v1 = pooled[b2 * C_ + 2 * k2 - 299];
          unsigned p0 = pack_split(v0), p1 = pack_split(v1);
          bpH[(size_t)r * KP_ + k2] = (p0 & 0xFFFFu) | (p1 << 16);
          bpL[(size_t)r * KP_ + k2] = (p0 >> 16) | (p1 & 0xFFFF0000u);
        }
      }
      flag_signal(&flags[FLG(D_PB)]);
    }
    flag_wait(&flags[FLG(D_PB)], NIT_PB);
    flag_wait(&flags[FLG(D_PW)], NIT_PW);
    flag_wait(&flags[FLG(D_PBE)], NIT_PB);

    // ---- GEMM tiles off the work queue, in LSTM-consumption priority order
    const int w = tid >> 6, l = tid & 63;
    const int lx = l & 15, lq = l >> 4;
    const int jr = tid >> 1, hh = tid & 1;
    const int q_st = jr >> 4, lane_lo = jr & 15;
    const int w0 = (q_st * 64 + lane_lo + 32 * hh) * 4;
    const int w1 = (q_st * 64 + lane_lo + 32 * hh + 16) * 4;
    unsigned* aH = sm.gemm.aH;
    unsigned* aL = sm.gemm.aL;
    unsigned* bH = sm.gemm.bH;
    unsigned* bL = sm.gemm.bL;

    for (;;) {
      __syncthreads();
      if (tid == 0)
        curq = __hip_atomic_fetch_add(&flags[FLG(Q_G)], 1, __ATOMIC_RELAXED,
                                      __HIP_MEMORY_SCOPE_AGENT);
      __syncthreads();
      const int g = curq;
      if (g >= NTILE_G) break;
      // d fastest; backward direction consumes t descending -> rt descending
      const int d = g & 1;
      const int jt = (g >> 1) & 7;
      const int rtb = g >> 4;
      const int rt = d ? (31 - rtb) : rtb;
      const int j0 = jt * 128, r0 = rt * 128;

      f32x4 acch[2][8], accl[2][8];
#pragma unroll
      for (int mt = 0; mt < 2; ++mt)
#pragma unroll
        for (int nt = 0; nt < 8; ++nt) {
          f32x4 z = {0.f, 0.f, 0.f, 0.f};
          acch[mt][nt] = z; accl[mt][nt] = z;
        }

      const unsigned* arH = apH + ((size_t)(d * G4_ + j0 + jr)) * KP_ + hh * 8;
      const unsigned* arL = apL + ((size_t)(d * G4_ + j0 + jr)) * KP_ + hh * 8;
      const unsigned* brH = bpH + ((size_t)(r0 + jr)) * KP_ + hh * 8;
      const unsigned* brL = bpL + ((size_t)(r0 + jr)) * KP_ + hh * 8;

      for (int Kt = 0; Kt < 13; ++Kt) {
        uint4 a0 = *(const uint4*)(arH + Kt * 16);
        uint4 a1 = *(const uint4*)(arH + Kt * 16 + 4);
        uint4 c0v = *(const uint4*)(arL + Kt * 16);
        uint4 c1v = *(const uint4*)(arL + Kt * 16 + 4);
        uint4 e0 = *(const uint4*)(brH + Kt * 16);
        uint4 e1 = *(const uint4*)(brH + Kt * 16 + 4);
        uint4 f0 = *(const uint4*)(brL + Kt * 16);
        uint4 f1 = *(const uint4*)(brL + Kt * 16 + 4);
        *(uint4*)&aH[w0] = a0; *(uint4*)&aH[w1] = a1;
        *(uint4*)&aL[w0] = c0v; *(uint4*)&aL[w1] = c1v;
        *(uint4*)&bH[w0] = e0; *(uint4*)&bH[w1] = e1;
        *(uint4*)&bL[w0] = f0; *(uint4*)&bL[w1] = f1;
        __syncthreads();

        union u4h { uint4 u; half8 h; };
        u4h AH0, AH1, AL0, AL1;
        AH0.u = *(const uint4*)&aH[((2 * w + 0) * 64 + l) * 4];
        AH1.u = *(const uint4*)&aH[((2 * w + 1) * 64 + l) * 4];
        AL0.u = *(const uint4*)&aL[((2 * w + 0) * 64 + l) * 4];
        AL1.u = *(const uint4*)&aL[((2 * w + 1) * 64 + l) * 4];
#pragma unroll
        for (int nt = 0; nt < 8; ++nt) {
          u4h BHn, BLn;
          BHn.u = *(const uint4*)&bH[(nt * 64 + l) * 4];
          BLn.u = *(const uint4*)&bL[(nt * 64 + l) * 4];
          acch[0][nt] = __builtin_amdgcn_mfma_f32_16x16x32_f16(AH0.h, BHn.h, acch[0][nt], 0, 0, 0);
          accl[0][nt] = __builtin_amdgcn_mfma_f32_16x16x32_f16(AH0.h, BLn.h, accl[0][nt], 0, 0, 0);
          accl[0][nt] = __builtin_amdgcn_mfma_f32_16x16x32_f16(AL0.h, BHn.h, accl[0][nt], 0, 0, 0);
          acch[1][nt] = __builtin_amdgcn_mfma_f32_16x16x32_f16(AH1.h, BHn.h, acch[1][nt], 0, 0, 0);
          accl[1][nt] = __builtin_amdgcn_mfma_f32_16x16x32_f16(AH1.h, BLn.h, accl[1][nt], 0, 0, 0);
          accl[1][nt] = __builtin_amdgcn_mfma_f32_16x16x32_f16(AL1.h, BHn.h, accl[1][nt], 0, 0, 0);
        }
        __syncthreads();
      }

      const float* bias = d ? b_b : b_f;
      const float inv2048 = 1.0f / 2048.0f;
#pragma unroll
      for (int mt = 0; mt < 2; ++mt) {
#pragma unroll
        for (int nt = 0; nt < 8; ++nt) {
          int rr = r0 + nt * 16 + lx;
          int tt = rr >> 5, bb2 = rr & 31;
          unsigned* dst = (unsigned*)gi + ((size_t)(d * S_ + tt) * G4_) * B_ + bb2;
#pragma unroll
          for (int r4 = 0; r4 < 4; ++r4) {
            int j = j0 + (2 * w + mt) * 16 + lq * 4 + r4;
            float vv = acch[mt][nt][r4] + accl[mt][nt][r4] * inv2048 + bias[j];
            __hip_atomic_store(&dst[(size_t)j * B_], __builtin_bit_cast(unsigned, vv),
                               __ATOMIC_RELAXED, __HIP_MEMORY_SCOPE_AGENT);
          }
        }
      }
      // release-signal this (d, rt) tile: 8 jt-blocks per tile -> LSTM waits for ==8
      flag_signal(&flags[FLG(FG(d, rt))]);
    }
    return;
  }
}

// ---------------------------------------------------------------- tail: FC (plain loads) + softmax/viterbi
__global__ __launch_bounds__(256) void k_tail(
    const int* __restrict__ x, const float* __restrict__ hbuf,
    const float* __restrict__ fc_w, const float* __restrict__ fc_b,
    const float* __restrict__ start_t, const float* __restrict__ trans,
    const float* __restrict__ end_t,
    float* __restrict__ em, int* __restrict__ flags, int* __restrict__ out) {
  const int bid = blockIdx.x;
  union SMemTail {
    struct { float wT[512 * 18]; float psum[256 * 18]; } fc;
    struct { float e[S_ * L_]; float tr[L_ * L_]; float sc[2][L_];
             int hist[(S_ - 1) * L_]; int tags[S_]; } smv;
  };
  __shared__ SMemTail sm;

  if (bid < TRB_SMV) {
    const int s = bid;
    const int tid = threadIdx.x;
    float* wT = sm.fc.wT;
    float* psum = sm.fc.psum;
    for (int i = tid; i < L_ * 512; i += 256) {
      int l2 = i / 512, k = i % 512;
      wT[k * 18 + l2] = fc_w[i];
    }
    __syncthreads();
    const int b2 = tid & 31, kq = tid >> 5;
    const float* hf = hbuf + (size_t)(s + 1) * (H_ * B_);
    const float* hbk = hbuf + (size_t)(S_ + 1 + (S_ - s)) * (H_ * B_);
    float acc[L_];
#pragma unroll
    for (int l2 = 0; l2 < L_; ++l2) acc[l2] = 0.f;
    for (int i = 0; i < 64; ++i) {
      int k = kq * 64 + i;
      float hv = (k < 256) ? hf[k * 32 + b2] : hbk[(k - 256) * 32 + b2];
      const float* wr = &wT[k * 18];
#pragma unroll
      for (int l2 = 0; l2 < L_; ++l2) acc[l2] = fmaf(hv, wr[l2], acc[l2]);
    }
#pragma unroll
    for (int l2 = 0; l2 < L_; ++l2) psum[tid * 18 + l2] = acc[l2];
    __syncthreads();
    for (int idx = tid; idx < B_ * L_; idx += 256) {
      int bb2 = idx & 31, l2 = idx >> 5;
      float sum = fc_b[l2];
      for (int q2 = 0; q2 < 8; ++q2) sum += psum[(q2 * 32 + bb2) * 18 + l2];
      em[((size_t)bb2 * S_ + s) * L_ + l2] = sum;
    }
    flag_signal(&flags[FLG(F_EM)]);
    return;
  } else {
    const int bb = bid - TRB_SMV;
    const int tid = threadIdx.x;
    float* e = sm.smv.e;
    float* tr = sm.smv.tr;
    auto sc = sm.smv.sc;
    int* hist = sm.smv.hist;
    int* tags = sm.smv.tags;

    if (tid == 0) flag_wait(&flags[FLG(F_EM)], TNB_FC);
    __syncthreads();
    for (int i = tid; i < S_ * L_; i += 256) e[i] = em[(size_t)bb * S_ * L_ + i];
    for (int i = tid; i < L_ * L_; i += 256) tr[i] = trans[i];
    __syncthreads();
    if (tid < L_) {
      int l2 = tid;
      float m = -INFINITY;
      for (int s2 = 0; s2 < S_; ++s2) m = fmaxf(m, e[s2 * L_ + l2]);
      float sum2 = 0.f;
      for (int s2 = 0; s2 < S_; ++s2) {
        float ex = expf(e[s2 * L_ + l2] - m);
        e[s2 * L_ + l2] = ex;
        sum2 += ex;
      }
      for (int s2 = 0; s2 < S_; ++s2) e[s2 * L_ + l2] = e[s2 * L_ + l2] / sum2;
    }
    __syncthreads();
    if (tid < L_) sc[0][tid] = start_t[tid] + e[tid];
    __syncthreads();
    int cbuf = 0;
    for (int t2 = 1; t2 < S_; ++t2) {
      if (tid < L_) {
        int j2 = tid;
        float evv = e[t2 * L_ + j2];
        float best = -INFINITY;
        int arg = 0;
        for (int i = 0; i < L_; ++i) {
          float v = (sc[cbuf][i] + tr[i * L_ + j2]) + evv;
          if (v > best) { best = v; arg = i; }  // strict >: first occurrence like np.argmax
        }
        int maskt = (x[bb * S_ + t2] != 0);
        sc[cbuf ^ 1][j2] = maskt ? best : sc[cbuf][j2];
        hist[(t2 - 1) * L_ + j2] = arg;
      }
      __syncthreads();
      cbuf ^= 1;
    }
    if (tid == 0) {
      float best = -INFINITY;
      int last = 0;
      for (int j2 = 0; j2 < L_; ++j2) {
        float v = sc[cbuf][j2] + end_t[j2];
        if (v > best) { best = v; last = j2; }
      }
      int cur = last;
      tags[S_ - 1] = cur;
      for (int p = S_ - 2; p >= 0; --p) {
        if (x[bb * S_ + p + 1] != 0) cur = hist[p * L_ + cur];
        tags[p] = cur;
      }
    }
    __syncthreads();
    for (int s2 = tid; s2 < S_; s2 += 256) out[bb * S_ + s2] = tags[s2];
    return;
  }
}

// ---------------------------------------------------------------- launch
extern "C" void kernel_launch(void* const* d_in, const int* in_sizes, int n_in,
                              void* d_out, int out_size, void* d_ws, size_t ws_size,
                              hipStream_t stream) {
  const int* x        = (const int*)d_in[0];
  const int* x_char   = (const int*)d_in[1];
  const float* word_emb = (const float*)d_in[2];
  const float* char_emb = (const float*)d_in[3];
  const float* conv1_w = (const float*)d_in[4];
  const float* conv1_b = (const float*)d_in[5];
  const float* conv2_w = (const float*)d_in[6];
  const float* conv2_b = (const float*)d_in[7];
  const float* conv3_w = (const float*)d_in[8];
  const float* conv3_b = (const float*)d_in[9];
  const float* w_ih_f = (const float*)d_in[10];
  const float* w_hh_f = (const float*)d_in[11];
  const float* b_f    = (const float*)d_in[12];
  const float* w_ih_b = (const float*)d_in[13];
  const float* w_hh_b = (const float*)d_in[14];
  const float* b_b    = (const float*)d_in[15];
  const float* h0     = (const float*)d_in[16];
  const float* c0     = (const float*)d_in[17];
  const float* fc_w   = (const float*)d_in[18];
  const float* fc_b   = (const float*)d_in[19];
  const float* start_t = (const float*)d_in[20];
  const float* trans  = (const float*)d_in[21];
  const float* end_t  = (const float*)d_in[22];
  int* out = (int*)d_out;

  char* ws = (char*)d_ws;
  auto alloc = [&](size_t bytes) -> char* {
    char* p = ws;
    ws += (bytes + 1023) & ~(size_t)1023;
    return p;
  };
  float* pooled  = (float*)alloc(sizeof(float) * B_ * C_);
  float* gi      = (float*)alloc(sizeof(float) * 2 * S_ * G4_ * B_);
  float* hbuf    = (float*)alloc(sizeof(float) * 2 * (S_ + 1) * H_ * B_);
  unsigned* hfrag = (unsigned*)alloc(sizeof(unsigned) * 2 * (S_ + 1) * SLAB_);
  unsigned* apH  = (unsigned*)alloc(sizeof(unsigned) * 2 * G4_ * KP_);
  unsigned* apL  = (unsigned*)alloc(sizeof(unsigned) * 2 * G4_ * KP_);
  unsigned* bpH  = (unsigned*)alloc(sizeof(unsigned) * 4096 * KP_);
  unsigned* bpL  = (unsigned*)alloc(sizeof(unsigned) * 4096 * KP_);
  float* out1    = (float*)alloc(sizeof(float) * B_ * C_ * 48);
  float* out2    = (float*)alloc(sizeof(float) * B_ * C_ * 45);
  float* em      = (float*)alloc(sizeof(float) * B_ * S_ * L_);
  int* flags     = (int*)alloc(sizeof(int) * NFLAGS_);

  hipMemsetAsync(flags, 0, sizeof(int) * NFLAGS_, stream);
  k_mega<<<NBLK_MEGA, 256, 0, stream>>>(
      x, x_char, word_emb, char_emb,
      conv1_w, conv1_b, conv2_w, conv2_b, conv3_w, conv3_b,
      w_ih_f, w_ih_b, w_hh_f, w_hh_b, b_f, b_b, h0, c0,
      pooled, gi, hbuf, hfrag, apH, apL, bpH, bpL, out1, out2, flags);
  k_tail<<<NBLK_TAIL, 256, 0, stream>>>(
      x, hbuf, fc_w, fc_b, start_t, trans, end_t, em, flags, out);
}

// Round 10
// 866.752 us; speedup vs baseline: 1.1207x; 1.1207x over previous
//
#include <hip/hip_runtime.h>
#include <cmath>

#define B_   32
#define S_   128
#define E_   300
#define C_   100
#define EC_  50
#define LC_  50
#define H_   256
#define G4_  1024   // 4*H
#define L_   17
#define DHID_ 400   // E + C
#define SLAB_ 8192  // u32 per (d,t) frag slab: [Nt(2)][Kt(8)][lane(64)][hi m0..3 | lo m4..7]
#define SENT2_ 0x7E007E00u  // fp16-NaN in both halves: legit packed pair never matches
#define KP_   208   // k-pairs per row in packed GEMM operands (416 k, zero-padded from 400)

// ---- k_misc role layout (independent roles, no flags, no LDS) ----
#define MRB_HINIT 0
#define MNB_HINIT 256
#define MRB_PW    256
#define MNB_PW    64
#define MRB_PB1   320
#define MNB_PB1   128
#define NBLK_MISC 448

// ---- k_gl layout: 32 LSTM blocks (exclusive CUs via 84KB pad) + 512 GEMM queue workers ----
#define NB_LSTM   32
#define NBLK_GL   544
#define NTILE_G   512

// ---- k_tail role layout ----
#define TRB_FC   0
#define TNB_FC   128
#define TRB_SMV  128
#define TNB_SMV  32
#define NBLK_TAIL 160

// flags: each id padded 32 ints (128 B) apart -> no false sharing
#define F_EM   7
#define FG(d, rt) (8 + (d) * 32 + (rt))   // 8..71, target 8 each
#define Q_G    78
#define FLG(i)    ((i) * 32)
#define NFLAGS_   (80 * 32)

typedef _Float16 half8 __attribute__((ext_vector_type(8)));
typedef float f32x4 __attribute__((ext_vector_type(4)));
typedef unsigned long long ull;
struct __align__(16) U2 { ull x, y; };

// split fp32 -> (hi fp16, lo fp16 scaled by 2048), packed u32 (hi in low16).
__device__ __forceinline__ unsigned pack_split(float v) {
  _Float16 hi = (fabsf(v) >= 6.104e-5f) ? (_Float16)v : (_Float16)0.0f;
  float hif = (float)hi;
  _Float16 lo = (_Float16)((v - hif) * 2048.0f);
  return (unsigned)__builtin_bit_cast(unsigned short, hi)
       | ((unsigned)__builtin_bit_cast(unsigned short, lo) << 16);
}

__device__ __forceinline__ void flag_signal(int* f) {
  __syncthreads();   // all threads' stores drained; release add -> LLC
  if (threadIdx.x == 0)
    __hip_atomic_fetch_add(f, 1, __ATOMIC_RELEASE, __HIP_MEMORY_SCOPE_AGENT);
}
__device__ __forceinline__ void flag_wait(const int* f, int target) {
  while (__hip_atomic_load(f, __ATOMIC_ACQUIRE, __HIP_MEMORY_SCOPE_AGENT) < target)
    __builtin_amdgcn_s_sleep(8);
}

// ---------------------------------------------------------------- misc: hfrag init + prep_w + prep_b phase1
// Roles are mutually independent -> no flags, no LDS, full occupancy. (R7 verbatim + full flag zeroing.)
__global__ void k_misc(const int* __restrict__ x, const float* __restrict__ word_emb,
                       const float* __restrict__ h0,
                       const float* __restrict__ w_ih_f, const float* __restrict__ w_ih_b,
                       unsigned* __restrict__ hfrag,
                       unsigned* __restrict__ apH, unsigned* __restrict__ apL,
                       unsigned* __restrict__ bpH, unsigned* __restrict__ bpL,
                       int* __restrict__ flags) {
  const int bid = blockIdx.x;
  const int tid = threadIdx.x;
  if (bid == 0) {
    for (int i = tid; i < NFLAGS_; i += 256) flags[i] = 0;  // consumed only by later kernels
  }

  if (bid < MRB_PW) {
    // hfrag: t=0 packed from h0, t>=1 sentinel
    const int g0 = bid * 256 + tid;
    const int nth = MNB_HINIT * 256;
    const int htot = 2 * (S_ + 1) * SLAB_;
    for (int idx = g0; idx < htot; idx += nth) {
      int sd = idx / SLAB_;
      int within = idx % SLAB_;
      int t = sd % (S_ + 1), d = sd / (S_ + 1);
      if (t != 0) { hfrag[idx] = SENT2_; continue; }
      int m8 = within & 7;
      int lane = (within >> 3) & 63;
      int q = within >> 9;
      int Kt = q & 7, Nt = q >> 3;
      int m = m8 & 3, isLo = m8 >> 2;
      int k0 = Kt * 32 + (lane >> 4) * 8 + 2 * m;
      int b = Nt * 16 + (lane & 15);
      unsigned p0 = pack_split(h0[((size_t)d * B_ + b) * H_ + k0]);
      unsigned p1 = pack_split(h0[((size_t)d * B_ + b) * H_ + k0 + 1]);
      unsigned hiw = (p0 & 0xFFFFu) | (p1 << 16);
      unsigned low = (p0 >> 16) | (p1 & 0xFFFF0000u);
      hfrag[idx] = isLo ? low : hiw;
    }
    return;
  } else if (bid < MRB_PB1) {
    // prep_w: w_ih -> hi/lo pair format
    const int q = bid - MRB_PW;
    const int total = 2 * G4_ * KP_;
    for (int idx = q * 256 + tid; idx < total; idx += MNB_PW * 256) {
      int d = idx / (G4_ * KP_);
      int rem = idx % (G4_ * KP_);
      int j = rem / KP_, k2 = rem % KP_;
      const float* w2 = d ? w_ih_b : w_ih_f;
      float v0 = 0.f, v1 = 0.f;
      if (k2 < 200) { v0 = w2[(size_t)j * DHID_ + 2 * k2]; v1 = w2[(size_t)j * DHID_ + 2 * k2 + 1]; }
      unsigned p0 = pack_split(v0), p1 = pack_split(v1);
      apH[idx] = (p0 & 0xFFFFu) | (p1 << 16);
      apL[idx] = (p0 >> 16) | (p1 & 0xFFFF0000u);
    }
    return;
  } else {
    // prep_b phase 1: emb part (k2<150) + zero pad (k2>=200)
    const int q = bid - MRB_PB1;
    if (tid < KP_) {
      int k2 = tid;
      for (int rr = 0; rr < 32; ++rr) {
        int r = q * 32 + rr;
        int t2 = r >> 5, b2 = r & 31;
        if (k2 < 150) {
          const float* e2 = word_emb + (size_t)x[b2 * S_ + t2] * E_;
          unsigned p0 = pack_split(e2[2 * k2]), p1 = pack_split(e2[2 * k2 + 1]);
          bpH[(size_t)r * KP_ + k2] = (p0 & 0xFFFFu) | (p1 << 16);
          bpL[(size_t)r * KP_ + k2] = (p0 >> 16) | (p1 & 0xFFFF0000u);
        } else if (k2 >= 200) {
          bpH[(size_t)r * KP_ + k2] = 0u;
          bpL[(size_t)r * KP_ + k2] = 0u;
        }
      }
    }
    return;
  }
}

// ---------------------------------------------------------------- char conv1 (R7 verbatim)
__global__ void k_conv1(const int* __restrict__ x_char, const float* __restrict__ char_emb,
                        const float* __restrict__ w1, const float* __restrict__ b1,
                        float* __restrict__ out1) {
  int b = blockIdx.x;
  int ot = blockIdx.y;
  __shared__ float ce[EC_ * 52];
  __shared__ float wl[50 * 150];
  __shared__ int ids[LC_];
  int tid = threadIdx.x;
  if (tid < LC_) ids[tid] = x_char[b * LC_ + tid];
  __syncthreads();
  for (int idx = tid; idx < LC_ * EC_; idx += 256) {
    int t = idx / EC_, ec = idx % EC_;
    ce[ec * 52 + t] = char_emb[ids[t] * EC_ + ec];
  }
  int obase = ot * 50;
  for (int idx = tid; idx < 50 * 150; idx += 256)
    wl[idx] = w1[obase * 150 + idx];
  __syncthreads();
  for (int idx = tid; idx < 50 * 48; idx += 256) {
    int o = idx / 48, t = idx % 48;
    float acc = b1[obase + o];
    const float* wr = &wl[o * 150];
    for (int c = 0; c < EC_; ++c) {
      const float* ip = &ce[c * 52 + t];
      acc += wr[c * 3 + 0] * ip[0] + wr[c * 3 + 1] * ip[1] + wr[c * 3 + 2] * ip[2];
    }
    out1[((size_t)b * C_ + obase + o) * 48 + t] = fmaxf(acc, 0.0f);
  }
}

// ---------------------------------------------------------------- char conv2 (R7 verbatim)
__global__ void k_conv2(const float* __restrict__ in, const float* __restrict__ w2,
                        const float* __restrict__ b2, float* __restrict__ out2) {
  int b = blockIdx.x, ot = blockIdx.y;
  __shared__ float il[C_ * 48];
  __shared__ float wl[25 * 400];
  int tid = threadIdx.x;
  for (int idx = tid; idx < C_ * 48; idx += 256) il[idx] = in[(size_t)b * C_ * 48 + idx];
  int obase = ot * 25;
  for (int idx = tid; idx < 25 * 400; idx += 256) wl[idx] = w2[obase * 400 + idx];
  __syncthreads();
  for (int idx = tid; idx < 25 * 45; idx += 256) {
    int o = idx / 45, t = idx % 45;
    float acc = b2[obase + o];
    const float* wr = &wl[o * 400];
    for (int c = 0; c < C_; ++c) {
      const float* ip = &il[c * 48 + t];
      acc += wr[c * 4 + 0] * ip[0] + wr[c * 4 + 1] * ip[1] +
             wr[c * 4 + 2] * ip[2] + wr[c * 4 + 3] * ip[3];
    }
    out2[((size_t)b * C_ + obase + o) * 45 + t] = fmaxf(acc, 0.0f);
  }
}

// ---------------------------------------------------------------- char conv3 + maxpool (R7 verbatim)
__global__ void k_conv3(const float* __restrict__ in, const float* __restrict__ w3,
                        const float* __restrict__ b3, float* __restrict__ pooled) {
  int b = blockIdx.x, ot = blockIdx.y;
  __shared__ float il[C_ * 45];
  __shared__ float wl[20 * 500];
  __shared__ float o3[20 * 44];
  int tid = threadIdx.x;
  for (int idx = tid; idx < C_ * 45; idx += 256) il[idx] = in[(size_t)b * C_ * 45 + idx];
  int obase = ot * 20;
  for (int idx = tid; idx < 20 * 500; idx += 256) wl[idx] = w3[obase * 500 + idx];
  __syncthreads();
  for (int idx = tid; idx < 20 * 41; idx += 256) {
    int o = idx / 41, t = idx % 41;
    float acc = b3[obase + o];
    const float* wr = &wl[o * 500];
    for (int c = 0; c < C_; ++c) {
      const float* ip = &il[c * 45 + t];
      acc += wr[c * 5 + 0] * ip[0] + wr[c * 5 + 1] * ip[1] + wr[c * 5 + 2] * ip[2] +
             wr[c * 5 + 3] * ip[3] + wr[c * 5 + 4] * ip[4];
    }
    o3[o * 44 + t] = fmaxf(acc, 0.0f);
  }
  __syncthreads();
  if (tid < 20) {
    float m = o3[tid * 44];
    for (int t = 1; t < 41; ++t) m = fmaxf(m, o3[tid * 44 + t]);
    pooled[b * C_ + obase + tid] = m;
  }
}

// ---------------------------------------------------------------- prep_b phase 2 (R7 verbatim)
__global__ void k_pb2(const float* __restrict__ pooled,
                      unsigned* __restrict__ bpH, unsigned* __restrict__ bpL) {
  const int q = blockIdx.x;
  const int k2 = threadIdx.x;
  if (k2 < 150 || k2 >= 200) return;
  for (int rr = 0; rr < 32; ++rr) {
    int r = q * 32 + rr;
    int b2 = r & 31;
    float v0 = pooled[b2 * C_ + 2 * k2 - 300];
    float v1 = pooled[b2 * C_ + 2 * k2 - 299];
    unsigned p0 = pack_split(v0), p1 = pack_split(v1);
    bpH[(size_t)r * KP_ + k2] = (p0 & 0xFFFFu) | (p1 << 16);
    bpL[(size_t)r * KP_ + k2] = (p0 >> 16) | (p1 & 0xFFFF0000u);
  }
}

// 84 KB pad forces 1 block/CU: the 32 LSTM blocks (bids 0..31, dispatched first) each
// get an exclusive CU; GEMM workers occupy the other 224 CUs, one each, draining the
// tile queue. This bounds interference to LLC traffic during the first ~40us only.
union SMemGL {
  char pad[84 * 1024];
  struct { unsigned aH[2048], aL[2048], bH[2048], bL[2048]; } gemm;                       // 32 KB
  struct { ull slh[2048], sll[2048]; float gl[4 * 16 * 33]; unsigned ps[2 * 576]; } lstm; // 45.3 KB
};

// ---------------------------------------------------------------- gl: LSTM (exclusive CUs) + GEMM workers
__global__ __launch_bounds__(256) void k_gl(
    const float* __restrict__ w_hh_f, const float* __restrict__ w_hh_b,
    const float* __restrict__ c0,
    const unsigned* __restrict__ apH, const unsigned* __restrict__ apL,
    const unsigned* __restrict__ bpH, const unsigned* __restrict__ bpL,
    const float* __restrict__ b_f, const float* __restrict__ b_b,
    float* __restrict__ gi, float* __restrict__ hbuf, unsigned* __restrict__ hfrag,
    int* __restrict__ flags) {
  const int bid = blockIdx.x;
  const int tid = threadIdx.x;
  __shared__ SMemGL sm;
  __shared__ int curq;

  // ================================================================ LSTM (bids 0..31) — R9-verified branch
  if (bid < NB_LSTM) {
    const int d = bid >> 4;
    const int iblk = bid & 15;
    const int Ktown = iblk >> 1;
    const int half = iblk & 1;
    const float* whh = d ? w_hh_b : w_hh_f;

    const int w = tid >> 6;             // wave index = gate (i,f,g,o)
    const int l = tid & 63;
    const int lx = l & 15, lq = l >> 4;
    const int u0 = iblk * 16;

    ull* slh = sm.lstm.slh;
    ull* sll = sm.lstm.sll;
    float* glb = sm.lstm.gl;
    unsigned* ps = sm.lstm.ps;

    half8 whi[8], wlo[8];
#pragma unroll
    for (int Kt = 0; Kt < 8; ++Kt) {
      int row = w * H_ + u0 + lx;
      int kk0 = Kt * 32 + lq * 8;
      const float* src = whh + (size_t)row * H_ + kk0;
      float4 f0 = *(const float4*)src;
      float4 f1 = *(const float4*)(src + 4);
      float wv[8] = {f0.x, f0.y, f0.z, f0.w, f1.x, f1.y, f1.z, f1.w};
      union { unsigned short s2[8]; half8 h; } HI, LO;
#pragma unroll
      for (int j = 0; j < 8; ++j) {
        float v = wv[j];
        _Float16 hi = (fabsf(v) >= 6.104e-5f) ? (_Float16)v : (_Float16)0.0f;
        float hif = (float)hi;
        _Float16 lo = (_Float16)((v - hif) * 2048.0f);
        HI.s2[j] = __builtin_bit_cast(unsigned short, hi);
        LO.s2[j] = __builtin_bit_cast(unsigned short, lo);
      }
      whi[Kt] = HI.h;
      wlo[Kt] = LO.h;
    }

    const int bc = tid & 31, cw = tid >> 5;
    float creg[2];
#pragma unroll
    for (int cu = 0; cu < 2; ++cu)
      creg[cu] = c0[((size_t)d * B_ + bc) * H_ + u0 + cu * 8 + cw];

    const int pNt = bc >> 4;
    const int pm = cw >> 1;
    const bool phi = (cw & 1) == 0;
    const int plane = bc & 15;
    const float inv2048 = 1.0f / 2048.0f;

    int rt_have = -1;
    for (int t = 0; t < S_; ++t) {
      int torig = d ? (S_ - 1 - t) : t;

      // gate on GEMM tile completion for this 4-step r-range (R3/R9-proven protocol)
      int rt = torig >> 2;
      if (rt != rt_have) {
        if (tid == 0) {
          const int* gf = &flags[FLG(FG(d, rt))];
          while (__hip_atomic_load(gf, __ATOMIC_ACQUIRE, __HIP_MEMORY_SCOPE_AGENT) < 8)
            __builtin_amdgcn_s_sleep(2);
        }
        __syncthreads();
        rt_have = rt;
      }

      // plain gi loads — in flight during the hfrag spin below
      f32x4 acch[2], accl[2];
      {
        const float* gbase = gi + ((size_t)(d * S_ + torig) * G4_) * B_;
#pragma unroll
        for (int Nt = 0; Nt < 2; ++Nt) {
          f32x4 v;
#pragma unroll
          for (int r = 0; r < 4; ++r) {
            int j = w * H_ + u0 + lq * 4 + r;
            v[r] = gbase[(size_t)j * B_ + Nt * 16 + lx];
          }
          acch[Nt] = v;
          f32x4 z = {0.f, 0.f, 0.f, 0.f};
          accl[Nt] = z;
        }
      }

      // spin on previous-step h fragments (unchanged protocol; full slab read)
      const ull* hp = (const ull*)(hfrag + (size_t)(d * (S_ + 1) + t) * SLAB_);
      ull pv[4][4];
#pragma unroll
      for (int c = 0; c < 4; ++c) {
        size_t base = ((size_t)(w * 4 + c) * 64 + l) * 4;
#pragma unroll
        for (int j = 0; j < 4; ++j)
          pv[c][j] = __hip_atomic_load(&hp[base + j], __ATOMIC_RELAXED,
                                       __HIP_MEMORY_SCOPE_AGENT);
      }
      for (;;) {
        bool pending = false;
#pragma unroll
        for (int c = 0; c < 4; ++c)
#pragma unroll
          for (int j = 0; j < 4; ++j)
            pending |= ((unsigned)pv[c][j] == SENT2_) |
                       ((unsigned)(pv[c][j] >> 32) == SENT2_);
        if (!pending) break;
#pragma unroll
        for (int c = 0; c < 4; ++c) {
          size_t base = ((size_t)(w * 4 + c) * 64 + l) * 4;
#pragma unroll
          for (int j = 0; j < 4; ++j)
            pv[c][j] = __hip_atomic_load(&hp[base + j], __ATOMIC_RELAXED,
                                         __HIP_MEMORY_SCOPE_AGENT);
        }
      }
#pragma unroll
      for (int c = 0; c < 4; ++c) {
        int idx = ((w * 4 + c) * 64 + l) * 2;
        U2 vh; vh.x = pv[c][0]; vh.y = pv[c][1];
        U2 vl; vl.x = pv[c][2]; vl.y = pv[c][3];
        *(U2*)&slh[idx] = vh;
        *(U2*)&sll[idx] = vl;
      }
      __syncthreads();

#pragma unroll
      for (int Kt = 0; Kt < 8; ++Kt) {
        half8 Bhi[2], Blo[2];
#pragma unroll
        for (int Nt = 0; Nt < 2; ++Nt) {
          int idx = ((Nt * 8 + Kt) * 64 + l) * 2;
          union { U2 u; half8 h; } UH, UL;
          UH.u = *(const U2*)&slh[idx];
          UL.u = *(const U2*)&sll[idx];
          Bhi[Nt] = UH.h;
          Blo[Nt] = UL.h;
        }
#pragma unroll
        for (int Nt = 0; Nt < 2; ++Nt) {
          acch[Nt] = __builtin_amdgcn_mfma_f32_16x16x32_f16(whi[Kt], Bhi[Nt], acch[Nt], 0, 0, 0);
          accl[Nt] = __builtin_amdgcn_mfma_f32_16x16x32_f16(whi[Kt], Blo[Nt], accl[Nt], 0, 0, 0);
          accl[Nt] = __builtin_amdgcn_mfma_f32_16x16x32_f16(wlo[Kt], Bhi[Nt], accl[Nt], 0, 0, 0);
        }
      }

#pragma unroll
      for (int Nt = 0; Nt < 2; ++Nt)
#pragma unroll
        for (int r = 0; r < 4; ++r) {
          int ul = lq * 4 + r;
          glb[(w * 16 + ul) * 33 + Nt * 16 + lx] = acch[Nt][r] + accl[Nt][r] * inv2048;
        }
      __syncthreads();

      float hreg[2];
#pragma unroll
      for (int cu = 0; cu < 2; ++cu) {
        int u = cu * 8 + cw;
        float g_i = glb[(0 * 16 + u) * 33 + bc];
        float g_f = glb[(1 * 16 + u) * 33 + bc];
        float g_g = glb[(2 * 16 + u) * 33 + bc];
        float g_o = glb[(3 * 16 + u) * 33 + bc];
        float si = 1.f / (1.f + __expf(-g_i));
        float sf = 1.f / (1.f + __expf(-g_f));
        float so = 1.f / (1.f + __expf(-g_o));
        float tg = 1.f - 2.f / (__expf(2.f * g_g) + 1.f);
        float cn = sf * creg[cu] + si * tg;
        float tc = 1.f - 2.f / (__expf(2.f * cn) + 1.f);
        float hn = so * tc;
        creg[cu] = cn;
        hreg[cu] = hn;
        unsigned me = pack_split(hn);
        unsigned pa = (unsigned)__shfl_xor((int)me, 32, 64);
        unsigned je = (cw & 1) ? pa : me;
        unsigned jo = (cw & 1) ? me : pa;
        unsigned hiw = (je & 0xFFFFu) | (jo << 16);
        unsigned low = (je >> 16) | (jo & 0xFFFF0000u);
        int lane2g = ((half * 2 + cu) << 4) | plane;
        int m8 = phi ? pm : (4 + pm);
        ps[pNt * 576 + lane2g * 9 + m8] = phi ? hiw : low;
      }
      __syncthreads();

      {
        ull* slab64 = (ull*)(hfrag + (size_t)(d * (S_ + 1) + t + 1) * SLAB_);
        int Nt = tid >> 7;
        int r = tid & 127;
        int lane2g = half * 32 + (r >> 2);
        int m2 = r & 3;
        unsigned a = ps[Nt * 576 + lane2g * 9 + 2 * m2];
        unsigned b2 = ps[Nt * 576 + lane2g * 9 + 2 * m2 + 1];
        ull v = (ull)a | ((ull)b2 << 32);
        __hip_atomic_store(&slab64[(size_t)(Nt * 8 + Ktown) * 256 + (size_t)half * 128 + r], v,
                           __ATOMIC_RELAXED, __HIP_MEMORY_SCOPE_AGENT);
        // hbuf: plain stores; consumer is k_tail (kernel-boundary coherence, R7-proven)
        float* hb = hbuf + (size_t)(d * (S_ + 1) + t + 1) * (H_ * B_) + u0 * B_;
        hb[0 * 256 + tid] = hreg[0];
        hb[1 * 256 + tid] = hreg[1];
      }
    }
    return;
  }

  // ================================================================ GEMM queue workers (bids 32..543)
  // Preps/convs all completed before this kernel launched -> no waits; pull tiles
  // off the queue in LSTM-consumption priority order. (R9-verified phase.)
  {
    const int w = tid >> 6, l = tid & 63;
    const int lx = l & 15, lq = l >> 4;
    const int jr = tid >> 1, hh = tid & 1;
    const int q_st = jr >> 4, lane_lo = jr & 15;
    const int w0 = (q_st * 64 + lane_lo + 32 * hh) * 4;
    const int w1 = (q_st * 64 + lane_lo + 32 * hh + 16) * 4;
    unsigned* aH = sm.gemm.aH;
    unsigned* aL = sm.gemm.aL;
    unsigned* bH = sm.gemm.bH;
    unsigned* bL = sm.gemm.bL;

    for (;;) {
      __syncthreads();
      if (tid == 0)
        curq = __hip_atomic_fetch_add(&flags[FLG(Q_G)], 1, __ATOMIC_RELAXED,
                                      __HIP_MEMORY_SCOPE_AGENT);
      __syncthreads();
      const int g = curq;
      if (g >= NTILE_G) break;
      // d fastest; backward direction consumes t descending -> rt descending
      const int d = g & 1;
      const int jt = (g >> 1) & 7;
      const int rtb = g >> 4;
      const int rt = d ? (31 - rtb) : rtb;
      const int j0 = jt * 128, r0 = rt * 128;

      f32x4 acch[2][8], accl[2][8];
#pragma unroll
      for (int mt = 0; mt < 2; ++mt)
#pragma unroll
        for (int nt = 0; nt < 8; ++nt) {
          f32x4 z = {0.f, 0.f, 0.f, 0.f};
          acch[mt][nt] = z; accl[mt][nt] = z;
        }

      const unsigned* arH = apH + ((size_t)(d * G4_ + j0 + jr)) * KP_ + hh * 8;
      const unsigned* arL = apL + ((size_t)(d * G4_ + j0 + jr)) * KP_ + hh * 8;
      const unsigned* brH = bpH + ((size_t)(r0 + jr)) * KP_ + hh * 8;
      const unsigned* brL = bpL + ((size_t)(r0 + jr)) * KP_ + hh * 8;

      for (int Kt = 0; Kt < 13; ++Kt) {
        uint4 a0 = *(const uint4*)(arH + Kt * 16);
        uint4 a1 = *(const uint4*)(arH + Kt * 16 + 4);
        uint4 c0v = *(const uint4*)(arL + Kt * 16);
        uint4 c1v = *(const uint4*)(arL + Kt * 16 + 4);
        uint4 e0 = *(const uint4*)(brH + Kt * 16);
        uint4 e1 = *(const uint4*)(brH + Kt * 16 + 4);
        uint4 f0 = *(const uint4*)(brL + Kt * 16);
        uint4 f1 = *(const uint4*)(brL + Kt * 16 + 4);
        *(uint4*)&aH[w0] = a0; *(uint4*)&aH[w1] = a1;
        *(uint4*)&aL[w0] = c0v; *(uint4*)&aL[w1] = c1v;
        *(uint4*)&bH[w0] = e0; *(uint4*)&bH[w1] = e1;
        *(uint4*)&bL[w0] = f0; *(uint4*)&bL[w1] = f1;
        __syncthreads();

        union u4h { uint4 u; half8 h; };
        u4h AH0, AH1, AL0, AL1;
        AH0.u = *(const uint4*)&aH[((2 * w + 0) * 64 + l) * 4];
        AH1.u = *(const uint4*)&aH[((2 * w + 1) * 64 + l) * 4];
        AL0.u = *(const uint4*)&aL[((2 * w + 0) * 64 + l) * 4];
        AL1.u = *(const uint4*)&aL[((2 * w + 1) * 64 + l) * 4];
#pragma unroll
        for (int nt = 0; nt < 8; ++nt) {
          u4h BHn, BLn;
          BHn.u = *(const uint4*)&bH[(nt * 64 + l) * 4];
          BLn.u = *(const uint4*)&bL[(nt * 64 + l) * 4];
          acch[0][nt] = __builtin_amdgcn_mfma_f32_16x16x32_f16(AH0.h, BHn.h, acch[0][nt], 0, 0, 0);
          accl[0][nt] = __builtin_amdgcn_mfma_f32_16x16x32_f16(AH0.h, BLn.h, accl[0][nt], 0, 0, 0);
          accl[0][nt] = __builtin_amdgcn_mfma_f32_16x16x32_f16(AL0.h, BHn.h, accl[0][nt], 0, 0, 0);
          acch[1][nt] = __builtin_amdgcn_mfma_f32_16x16x32_f16(AH1.h, BHn.h, acch[1][nt], 0, 0, 0);
          accl[1][nt] = __builtin_amdgcn_mfma_f32_16x16x32_f16(AH1.h, BLn.h, accl[1][nt], 0, 0, 0);
          accl[1][nt] = __builtin_amdgcn_mfma_f32_16x16x32_f16(AL1.h, BHn.h, accl[1][nt], 0, 0, 0);
        }
        __syncthreads();
      }

      const float* bias = d ? b_b : b_f;
      const float inv2048 = 1.0f / 2048.0f;
#pragma unroll
      for (int mt = 0; mt < 2; ++mt) {
#pragma unroll
        for (int nt = 0; nt < 8; ++nt) {
          int rr = r0 + nt * 16 + lx;
          int tt = rr >> 5, bb2 = rr & 31;
          unsigned* dst = (unsigned*)gi + ((size_t)(d * S_ + tt) * G4_) * B_ + bb2;
#pragma unroll
          for (int r4 = 0; r4 < 4; ++r4) {
            int j = j0 + (2 * w + mt) * 16 + lq * 4 + r4;
            float vv = acch[mt][nt][r4] + accl[mt][nt][r4] * inv2048 + bias[j];
            __hip_atomic_store(&dst[(size_t)j * B_], __builtin_bit_cast(unsigned, vv),
                               __ATOMIC_RELAXED, __HIP_MEMORY_SCOPE_AGENT);
          }
        }
      }
      // release-signal this (d, rt) tile: 8 jt-blocks per tile -> LSTM waits for ==8
      flag_signal(&flags[FLG(FG(d, rt))]);
    }
    return;
  }
}

// ---------------------------------------------------------------- tail: FC (plain loads) + softmax/viterbi (R7 verbatim)
__global__ __launch_bounds__(256) void k_tail(
    const int* __restrict__ x, const float* __restrict__ hbuf,
    const float* __restrict__ fc_w, const float* __restrict__ fc_b,
    const float* __restrict__ start_t, const float* __restrict__ trans,
    const float* __restrict__ end_t,
    float* __restrict__ em, int* __restrict__ flags, int* __restrict__ out) {
  const int bid = blockIdx.x;
  union SMemTail {
    struct { float wT[512 * 18]; float psum[256 * 18]; } fc;
    struct { float e[S_ * L_]; float tr[L_ * L_]; float sc[2][L_];
             int hist[(S_ - 1) * L_]; int tags[S_]; } smv;
  };
  __shared__ SMemTail sm;

  if (bid < TRB_SMV) {
    const int s = bid;
    const int tid = threadIdx.x;
    float* wT = sm.fc.wT;
    float* psum = sm.fc.psum;
    for (int i = tid; i < L_ * 512; i += 256) {
      int l2 = i / 512, k = i % 512;
      wT[k * 18 + l2] = fc_w[i];
    }
    __syncthreads();
    const int b2 = tid & 31, kq = tid >> 5;
    const float* hf = hbuf + (size_t)(s + 1) * (H_ * B_);
    const float* hbk = hbuf + (size_t)(S_ + 1 + (S_ - s)) * (H_ * B_);
    float acc[L_];
#pragma unroll
    for (int l2 = 0; l2 < L_; ++l2) acc[l2] = 0.f;
    for (int i = 0; i < 64; ++i) {
      int k = kq * 64 + i;
      float hv = (k < 256) ? hf[k * 32 + b2] : hbk[(k - 256) * 32 + b2];
      const float* wr = &wT[k * 18];
#pragma unroll
      for (int l2 = 0; l2 < L_; ++l2) acc[l2] = fmaf(hv, wr[l2], acc[l2]);
    }
#pragma unroll
    for (int l2 = 0; l2 < L_; ++l2) psum[tid * 18 + l2] = acc[l2];
    __syncthreads();
    for (int idx = tid; idx < B_ * L_; idx += 256) {
      int bb2 = idx & 31, l2 = idx >> 5;
      float sum = fc_b[l2];
      for (int q2 = 0; q2 < 8; ++q2) sum += psum[(q2 * 32 + bb2) * 18 + l2];
      em[((size_t)bb2 * S_ + s) * L_ + l2] = sum;
    }
    flag_signal(&flags[FLG(F_EM)]);
    return;
  } else {
    const int bb = bid - TRB_SMV;
    const int tid = threadIdx.x;
    float* e = sm.smv.e;
    float* tr = sm.smv.tr;
    auto sc = sm.smv.sc;
    int* hist = sm.smv.hist;
    int* tags = sm.smv.tags;

    if (tid == 0) flag_wait(&flags[FLG(F_EM)], TNB_FC);
    __syncthreads();
    for (int i = tid; i < S_ * L_; i += 256) e[i] = em[(size_t)bb * S_ * L_ + i];
    for (int i = tid; i < L_ * L_; i += 256) tr[i] = trans[i];
    __syncthreads();
    if (tid < L_) {
      int l2 = tid;
      float m = -INFINITY;
      for (int s2 = 0; s2 < S_; ++s2) m = fmaxf(m, e[s2 * L_ + l2]);
      float sum2 = 0.f;
      for (int s2 = 0; s2 < S_; ++s2) {
        float ex = expf(e[s2 * L_ + l2] - m);
        e[s2 * L_ + l2] = ex;
        sum2 += ex;
      }
      for (int s2 = 0; s2 < S_; ++s2) e[s2 * L_ + l2] = e[s2 * L_ + l2] / sum2;
    }
    __syncthreads();
    if (tid < L_) sc[0][tid] = start_t[tid] + e[tid];
    __syncthreads();
    int cbuf = 0;
    for (int t2 = 1; t2 < S_; ++t2) {
      if (tid < L_) {
        int j2 = tid;
        float evv = e[t2 * L_ + j2];
        float best = -INFINITY;
        int arg = 0;
        for (int i = 0; i < L_; ++i) {
          float v = (sc[cbuf][i] + tr[i * L_ + j2]) + evv;
          if (v > best) { best = v; arg = i; }  // strict >: first occurrence like np.argmax
        }
        int maskt = (x[bb * S_ + t2] != 0);
        sc[cbuf ^ 1][j2] = maskt ? best : sc[cbuf][j2];
        hist[(t2 - 1) * L_ + j2] = arg;
      }
      __syncthreads();
      cbuf ^= 1;
    }
    if (tid == 0) {
      float best = -INFINITY;
      int last = 0;
      for (int j2 = 0; j2 < L_; ++j2) {
        float v = sc[cbuf][j2] + end_t[j2];
        if (v > best) { best = v; last = j2; }
      }
      int cur = last;
      tags[S_ - 1] = cur;
      for (int p = S_ - 2; p >= 0; --p) {
        if (x[bb * S_ + p + 1] != 0) cur = hist[p * L_ + cur];
        tags[p] = cur;
      }
    }
    __syncthreads();
    for (int s2 = tid; s2 < S_; s2 += 256) out[bb * S_ + s2] = tags[s2];
    return;
  }
}

// ---------------------------------------------------------------- launch
extern "C" void kernel_launch(void* const* d_in, const int* in_sizes, int n_in,
                              void* d_out, int out_size, void* d_ws, size_t ws_size,
                              hipStream_t stream) {
  const int* x        = (const int*)d_in[0];
  const int* x_char   = (const int*)d_in[1];
  const float* word_emb = (const float*)d_in[2];
  const float* char_emb = (const float*)d_in[3];
  const float* conv1_w = (const float*)d_in[4];
  const float* conv1_b = (const float*)d_in[5];
  const float* conv2_w = (const float*)d_in[6];
  const float* conv2_b = (const float*)d_in[7];
  const float* conv3_w = (const float*)d_in[8];
  const float* conv3_b = (const float*)d_in[9];
  const float* w_ih_f = (const float*)d_in[10];
  const float* w_hh_f = (const float*)d_in[11];
  const float* b_f    = (const float*)d_in[12];
  const float* w_ih_b = (const float*)d_in[13];
  const float* w_hh_b = (const float*)d_in[14];
  const float* b_b    = (const float*)d_in[15];
  const float* h0     = (const float*)d_in[16];
  const float* c0     = (const float*)d_in[17];
  const float* fc_w   = (const float*)d_in[18];
  const float* fc_b   = (const float*)d_in[19];
  const float* start_t = (const float*)d_in[20];
  const float* trans  = (const float*)d_in[21];
  const float* end_t  = (const float*)d_in[22];
  int* out = (int*)d_out;

  char* ws = (char*)d_ws;
  auto alloc = [&](size_t bytes) -> char* {
    char* p = ws;
    ws += (bytes + 1023) & ~(size_t)1023;
    return p;
  };
  float* pooled  = (float*)alloc(sizeof(float) * B_ * C_);
  float* gi      = (float*)alloc(sizeof(float) * 2 * S_ * G4_ * B_);
  float* hbuf    = (float*)alloc(sizeof(float) * 2 * (S_ + 1) * H_ * B_);
  unsigned* hfrag = (unsigned*)alloc(sizeof(unsigned) * 2 * (S_ + 1) * SLAB_);
  unsigned* apH  = (unsigned*)alloc(sizeof(unsigned) * 2 * G4_ * KP_);
  unsigned* apL  = (unsigned*)alloc(sizeof(unsigned) * 2 * G4_ * KP_);
  unsigned* bpH  = (unsigned*)alloc(sizeof(unsigned) * 4096 * KP_);
  unsigned* bpL  = (unsigned*)alloc(sizeof(unsigned) * 4096 * KP_);
  float* out1    = (float*)alloc(sizeof(float) * B_ * C_ * 48);
  float* out2    = (float*)alloc(sizeof(float) * B_ * C_ * 45);
  float* em      = (float*)alloc(sizeof(float) * B_ * S_ * L_);
  int* flags     = (int*)alloc(sizeof(int) * NFLAGS_);

  k_misc<<<NBLK_MISC, 256, 0, stream>>>(x, word_emb, h0, w_ih_f, w_ih_b,
                                        hfrag, apH, apL, bpH, bpL, flags);
  k_conv1<<<dim3(32, 2), 256, 0, stream>>>(x_char, char_emb, conv1_w, conv1_b, out1);
  k_conv2<<<dim3(32, 4), 256, 0, stream>>>(out1, conv2_w, conv2_b, out2);
  k_conv3<<<dim3(32, 5), 256, 0, stream>>>(out2, conv3_w, conv3_b, pooled);
  k_pb2<<<128, 256, 0, stream>>>(pooled, bpH, bpL);
  k_gl<<<NBLK_GL, 256, 0, stream>>>(w_hh_f, w_hh_b, c0, apH, apL, bpH, bpL,
                                    b_f, b_b, gi, hbuf, hfrag, flags);
  k_tail<<<NBLK_TAIL, 256, 0, stream>>>(
      x, hbuf, fc_w, fc_b, start_t, trans, end_t, em, flags, out);
}